// Round 11
// baseline (9202.374 us; speedup 1.0000x reference)
//
#include <hip/hip_runtime.h>
#include <math.h>

#define VOC 32000
#define HID 512
#define BAT 32
#define SEQ 64

// ---- ws layout (BYTE offsets), all f32 unless noted ----
#define B_EIHT 0u          // [512][2048] enc Wih^T
#define B_EHHT 4194304u    // [512][2048] enc Whh^T
#define B_DIHT 8388608u    // [512][2048] dec Wih^T
#define B_DHHT 12582912u   // [512][2048] dec Whh^T
#define B_XD   16777216u   // [2048][2048] enc x-dots (no biases), r=b*64+t
#define B_H    33554432u   // [2][32][512] ping-pong h
#define B_C    33685504u   // [2][32][512]
#define B_E    33816576u   // [32][512] decoder input embedding
#define B_GT   33882112u   // [32][2048] gates
#define B_LG   34144256u   // [32][32000] logits, then shifted
#define B_PM   38240256u   // [32][512] partial max
#define B_PS   38305792u   // [32][512] partial sums
#define B_PK   38371328u   // u64 [32][512] argmax partials
#define B_M    38502400u   // [32] row max
#define B_LS   38502528u   // [32] lse
#define B_TK   38502656u   // int [32] tokens
// total ~38.5 MB

// ---- d_out layout (f32 element offsets) ----
#define OUT_TOK  0u
#define OUT_LOGP 2048u
#define OUT_ENC  65538048u

__device__ __forceinline__ unsigned long long packkey(float x, int v) {
    unsigned int fb = __float_as_uint(x);
    unsigned int key = (fb & 0x80000000u) ? ~fb : (fb | 0x80000000u);
    return ((unsigned long long)key << 32) | (unsigned int)(~(unsigned int)v);
}
__device__ __forceinline__ float sigf(float x) { return 1.0f / (1.0f + expf(-x)); }

// ---- transpose f32 [2048][512] -> [512][2048]
__global__ void k_tr(const float* __restrict__ src, float* __restrict__ dst) {
    __shared__ float lds[32][33];
    int c0 = blockIdx.x * 32, r0 = blockIdx.y * 32;
    int cl = threadIdx.x & 31, r8 = threadIdx.x >> 5;
    for (int rr = 0; rr < 4; ++rr) {
        int r = r8 + rr * 8;
        lds[r][cl] = src[(size_t)(r0 + r) * HID + c0 + cl];
    }
    __syncthreads();
    for (int rr = 0; rr < 4; ++rr) {
        int idx = threadIdx.x + rr * 256;
        int rl = idx & 31, c2 = idx >> 5;
        dst[(size_t)(c0 + c2) * 2048 + r0 + rl] = lds[rl][c2];
    }
}

// ---- zero parity-0 h,c
__global__ void k_zero(char* __restrict__ ws) {
    int i = blockIdx.x * 256 + threadIdx.x;   // 16384
    ((float*)(ws + B_H))[i] = 0.f;
    ((float*)(ws + B_C))[i] = 0.f;
}

// ---- enc x-dots: XD[r][j4] = fmaf-chain_k( WihT[k][j4] * emb[x[r]][k] )
__global__ void __launch_bounds__(256) k_xd(const int* __restrict__ x, const float* __restrict__ emb,
                                            char* __restrict__ ws) {
    __shared__ float e_s[512];
    int r = blockIdx.x;                        // 0..2047 (= b*64+t)
    int j4 = blockIdx.y * 256 + threadIdx.x;   // 0..2047
    const float* erow = emb + (size_t)x[r] * HID;
    for (int k = threadIdx.x; k < HID; k += 256) e_s[k] = erow[k];
    __syncthreads();
    const float* WT = (const float*)(ws + B_EIHT);
    float acc = 0.f;
    for (int k = 0; k < HID; ++k)
        acc = fmaf(WT[(size_t)k * 2048 + j4], e_s[k], acc);
    ((float*)(ws + B_XD))[(size_t)r * 2048 + j4] = acc;
}

// ---- gates: g = ((xdot + hdot) + bih) + bhh     (all f32, chains ascending k)
__global__ void __launch_bounds__(256) k_gates(const float* __restrict__ bih,
                                               const float* __restrict__ bhh,
                                               const float* __restrict__ Hin,
                                               char* __restrict__ ws, int t, int mode) {
    __shared__ float h_s[512];
    __shared__ float e_s[512];
    int b = blockIdx.x & 31, jb = blockIdx.x >> 5;
    int j4 = jb * 256 + threadIdx.x;
    for (int k = threadIdx.x; k < HID; k += 256) {
        h_s[k] = Hin[b * HID + k];
        if (mode == 1) e_s[k] = ((const float*)(ws + B_E))[b * HID + k];
    }
    __syncthreads();
    float xd;
    if (mode == 0) {
        xd = ((const float*)(ws + B_XD))[(size_t)(b * SEQ + t) * 2048 + j4];
    } else {
        const float* WT = (const float*)(ws + B_DIHT);
        float a = 0.f;
        for (int k = 0; k < HID; ++k)
            a = fmaf(WT[(size_t)k * 2048 + j4], e_s[k], a);
        xd = a;
    }
    const float* WH = (const float*)(ws + (mode == 0 ? B_EHHT : B_DHHT));
    float hd = 0.f;
    for (int k = 0; k < HID; ++k)
        hd = fmaf(WH[(size_t)k * 2048 + j4], h_s[k], hd);
    float g = (xd + hd) + bih[j4];
    g = g + bhh[j4];
    ((float*)(ws + B_GT))[b * 2048 + j4] = g;
}

// ---- cell: f32 per-op
__global__ void k_cell(char* __restrict__ ws,
                       const float* __restrict__ Cin,
                       float* __restrict__ Hout, float* __restrict__ Cout,
                       float* __restrict__ dout, int t, int mode) {
    int i = blockIdx.x * 256 + threadIdx.x;   // 16384
    int b = i >> 9, j = i & 511;
    const float* gb = (const float*)(ws + B_GT) + b * 2048;
    float ip = sigf(gb[j]);
    float fp = sigf(gb[512 + j]);
    float gp = tanhf(gb[1024 + j]);
    float op = sigf(gb[1536 + j]);
    float cn = fp * Cin[i] + ip * gp;          // f32: mul, mul, add (fma-contraction off for exactness)
    float hn = op * tanhf(cn);
    Hout[i] = hn;
    Cout[i] = cn;
    if (mode == 0)
        dout[OUT_ENC + (size_t)b * (SEQ * HID) + (size_t)t * HID + j] = hn;
}

// ---- decoder input gather
__global__ void k_embt(const int* __restrict__ sos, const float* __restrict__ emb,
                       char* __restrict__ ws, int t) {
    int b = blockIdx.x;
    int tok = (t == 0) ? sos[0] : ((const int*)(ws + B_TK))[b];
    const float* erow = emb + (size_t)tok * HID;
    for (int k = threadIdx.x; k < HID; k += 256)
        ((float*)(ws + B_E))[b * HID + k] = erow[k];
}

// ---- logits: per (v, 16-batch-half): ascending-k fmaf chain + bias; store + partial row max
__global__ void __launch_bounds__(256) k_logits(const float* __restrict__ Hin,
                                                const float* __restrict__ Wout,
                                                const float* __restrict__ bout,
                                                char* __restrict__ ws) {
    __shared__ float h2[16][512];             // 32 KiB
    int vb = blockIdx.x, bh = blockIdx.y;     // vb 0..124, bh 0..1
    for (int i = threadIdx.x; i < 16 * 512; i += 256) {
        int bb = i >> 9, k = i & 511;
        h2[bb][k] = Hin[(bh * 16 + bb) * HID + k];
    }
    __syncthreads();
    int v = vb * 256 + threadIdx.x;
    const float* wr = Wout + (size_t)v * HID;
    float acc[16];
#pragma unroll
    for (int i = 0; i < 16; ++i) acc[i] = 0.f;
    for (int k = 0; k < HID; k += 4) {
        float4 w = *(const float4*)&wr[k];
#pragma unroll
        for (int bb = 0; bb < 16; ++bb) {
            float4 h4 = *(const float4*)&h2[bb][k];
            float a = acc[bb];
            a = fmaf(w.x, h4.x, a);           // strictly ascending k, single accumulator
            a = fmaf(w.y, h4.y, a);
            a = fmaf(w.z, h4.z, a);
            a = fmaf(w.w, h4.w, a);
            acc[bb] = a;
        }
    }
    float bq = bout[v];
    float mx[16];
#pragma unroll
    for (int bb = 0; bb < 16; ++bb) {
        float lg = acc[bb] + bq;
        ((float*)(ws + B_LG))[(size_t)(bh * 16 + bb) * VOC + v] = lg;
        mx[bb] = lg;
    }
#pragma unroll
    for (int m = 1; m < 64; m <<= 1)
#pragma unroll
        for (int bb = 0; bb < 16; ++bb) mx[bb] = fmaxf(mx[bb], __shfl_xor(mx[bb], m));
    if ((threadIdx.x & 63) == 0) {
        int col = vb * 4 + (threadIdx.x >> 6);
#pragma unroll
        for (int bb = 0; bb < 16; ++bb)
            ((float*)(ws + B_PM))[(bh * 16 + bb) * 512 + col] = mx[bb];
    }
}

// ---- row max
__global__ void k_finM(char* __restrict__ ws) {
    __shared__ float sh[4];
    int b = blockIdx.x;
    float m = -3.4e38f;
    for (int c = threadIdx.x; c < 500; c += 256)
        m = fmaxf(m, ((const float*)(ws + B_PM))[b * 512 + c]);
#pragma unroll
    for (int k = 1; k < 64; k <<= 1) m = fmaxf(m, __shfl_xor(m, k));
    if ((threadIdx.x & 63) == 0) sh[threadIdx.x >> 6] = m;
    __syncthreads();
    if (threadIdx.x == 0)
        ((float*)(ws + B_M))[b] = fmaxf(fmaxf(sh[0], sh[1]), fmaxf(sh[2], sh[3]));
}

// ---- shifted = lg - m (f32, stored back); e = expf(shifted); partial sums
__global__ void __launch_bounds__(256) k_passB(char* __restrict__ ws) {
    int vb = blockIdx.x, bg = blockIdx.y;
    int b0 = bg * 2;
    int v = vb * 256 + threadIdx.x;
    float e2[2];
#pragma unroll
    for (int row = 0; row < 2; ++row) {
        int b = b0 + row;
        float m = ((const float*)(ws + B_M))[b];
        float* p = (float*)(ws + B_LG) + (size_t)b * VOC + v;
        float sv = *p - m;
        *p = sv;
        e2[row] = expf(sv);
    }
#pragma unroll
    for (int m = 1; m < 64; m <<= 1) {
        e2[0] += __shfl_xor(e2[0], m);
        e2[1] += __shfl_xor(e2[1], m);
    }
    if ((threadIdx.x & 63) == 0) {
        int col = vb * 4 + (threadIdx.x >> 6);
        ((float*)(ws + B_PS))[b0 * 512 + col] = e2[0];
        ((float*)(ws + B_PS))[(b0 + 1) * 512 + col] = e2[1];
    }
}

// ---- L = logf(sum)
__global__ void k_finS(char* __restrict__ ws) {
    __shared__ float sh[4];
    int b = blockIdx.x;
    float s = 0.f;
    for (int c = threadIdx.x; c < 500; c += 256)
        s += ((const float*)(ws + B_PS))[b * 512 + c];
#pragma unroll
    for (int k = 1; k < 64; k <<= 1) s += __shfl_xor(s, k);
    if ((threadIdx.x & 63) == 0) sh[threadIdx.x >> 6] = s;
    __syncthreads();
    if (threadIdx.x == 0)
        ((float*)(ws + B_LS))[b] = logf(sh[0] + sh[1] + sh[2] + sh[3]);
}

// ---- logp = shifted - L (f32) -> out ; argmax partials on final f32 logp (first-index ties)
__global__ void __launch_bounds__(256) k_passC(char* __restrict__ ws, float* __restrict__ dout, int t) {
    int vb = blockIdx.x, bg = blockIdx.y;
    int b0 = bg * 2;
    int v = vb * 256 + threadIdx.x;
    unsigned long long pk2[2];
#pragma unroll
    for (int row = 0; row < 2; ++row) {
        int b = b0 + row;
        float L = ((const float*)(ws + B_LS))[b];
        float sv = ((const float*)(ws + B_LG))[(size_t)b * VOC + v];
        float lp = sv - L;
        dout[OUT_LOGP + (size_t)(b * SEQ + t) * VOC + v] = lp;
        pk2[row] = packkey(lp, v);
    }
#pragma unroll
    for (int m = 1; m < 64; m <<= 1) {
#pragma unroll
        for (int row = 0; row < 2; ++row) {
            unsigned long long o = __shfl_xor(pk2[row], m);
            if (o > pk2[row]) pk2[row] = o;
        }
    }
    if ((threadIdx.x & 63) == 0) {
        int col = vb * 4 + (threadIdx.x >> 6);
        ((unsigned long long*)(ws + B_PK))[b0 * 512 + col] = pk2[0];
        ((unsigned long long*)(ws + B_PK))[(b0 + 1) * 512 + col] = pk2[1];
    }
}

// ---- token reduce
__global__ void k_finT(char* __restrict__ ws, float* __restrict__ dout, int t) {
    __shared__ unsigned long long sh[4];
    int b = blockIdx.x;
    unsigned long long pk = 0ull;
    for (int c = threadIdx.x; c < 500; c += 256) {
        unsigned long long o = ((const unsigned long long*)(ws + B_PK))[b * 512 + c];
        if (o > pk) pk = o;
    }
#pragma unroll
    for (int k = 1; k < 64; k <<= 1) {
        unsigned long long o = __shfl_xor(pk, k);
        if (o > pk) pk = o;
    }
    if ((threadIdx.x & 63) == 0) sh[threadIdx.x >> 6] = pk;
    __syncthreads();
    if (threadIdx.x == 0) {
        pk = sh[0];
        if (sh[1] > pk) pk = sh[1];
        if (sh[2] > pk) pk = sh[2];
        if (sh[3] > pk) pk = sh[3];
        int v = (int)(~(unsigned)(pk & 0xFFFFFFFFull));
        ((int*)(ws + B_TK))[b] = v;
        dout[OUT_TOK + b * SEQ + t] = (float)v;
    }
}

extern "C" void kernel_launch(void* const* d_in, const int* in_sizes, int n_in,
                              void* d_out, int out_size, void* d_ws, size_t ws_size,
                              hipStream_t stream) {
    const int*   x    = (const int*)d_in[0];
    const float* emb  = (const float*)d_in[1];
    const float* eWih = (const float*)d_in[2];
    const float* eWhh = (const float*)d_in[3];
    const float* ebih = (const float*)d_in[4];
    const float* ebhh = (const float*)d_in[5];
    const float* dWih = (const float*)d_in[6];
    const float* dWhh = (const float*)d_in[7];
    const float* dbih = (const float*)d_in[8];
    const float* dbhh = (const float*)d_in[9];
    const float* Wout = (const float*)d_in[10];
    const float* bout = (const float*)d_in[11];
    const int*   sos  = (const int*)d_in[12];
    float* out = (float*)d_out;
    char*  ws  = (char*)d_ws;

    float* H = (float*)(ws + B_H);   // parity stride 16384 floats
    float* C = (float*)(ws + B_C);

    hipLaunchKernelGGL(k_tr, dim3(16, 64), dim3(256), 0, stream, eWih, (float*)(ws + B_EIHT));
    hipLaunchKernelGGL(k_tr, dim3(16, 64), dim3(256), 0, stream, eWhh, (float*)(ws + B_EHHT));
    hipLaunchKernelGGL(k_tr, dim3(16, 64), dim3(256), 0, stream, dWih, (float*)(ws + B_DIHT));
    hipLaunchKernelGGL(k_tr, dim3(16, 64), dim3(256), 0, stream, dWhh, (float*)(ws + B_DHHT));
    hipLaunchKernelGGL(k_xd, dim3(2048, 8), dim3(256), 0, stream, x, emb, ws);
    hipLaunchKernelGGL(k_zero, dim3(64), dim3(256), 0, stream, ws);

    for (int t = 0; t < SEQ; ++t) {
        int pi = t & 1, po = pi ^ 1;
        hipLaunchKernelGGL(k_gates, dim3(256), dim3(256), 0, stream,
                           ebih, ebhh, H + pi * 16384, ws, t, 0);
        hipLaunchKernelGGL(k_cell, dim3(64), dim3(256), 0, stream,
                           ws, C + pi * 16384, H + po * 16384, C + po * 16384, out, t, 0);
    }
    for (int t = 0; t < SEQ; ++t) {
        int pi = t & 1, po = pi ^ 1;
        hipLaunchKernelGGL(k_embt, dim3(32), dim3(256), 0, stream, sos, emb, ws, t);
        hipLaunchKernelGGL(k_gates, dim3(256), dim3(256), 0, stream,
                           dbih, dbhh, H + pi * 16384, ws, t, 1);
        hipLaunchKernelGGL(k_cell, dim3(64), dim3(256), 0, stream,
                           ws, C + pi * 16384, H + po * 16384, C + po * 16384, out, t, 1);
        hipLaunchKernelGGL(k_logits, dim3(125, 2), dim3(256), 0, stream,
                           H + po * 16384, Wout, bout, ws);
        hipLaunchKernelGGL(k_finM, dim3(32), dim3(256), 0, stream, ws);
        hipLaunchKernelGGL(k_passB, dim3(125, 16), dim3(256), 0, stream, ws);
        hipLaunchKernelGGL(k_finS, dim3(32), dim3(256), 0, stream, ws);
        hipLaunchKernelGGL(k_passC, dim3(125, 16), dim3(256), 0, stream, ws, out, t);
        hipLaunchKernelGGL(k_finT, dim3(32), dim3(256), 0, stream, ws, out, t);
    }
}

// Round 12
// 8866.093 us; speedup vs baseline: 1.0379x; 1.0379x over previous
//
#include <hip/hip_runtime.h>
#include <math.h>

#define VOC 32000
#define HID 512
#define BAT 32
#define SEQ 64

// ---- ws layout (BYTE offsets), all f32 unless noted ----
#define B_EIHT 0u          // [512][2048] enc Wih^T
#define B_EHHT 4194304u    // [512][2048] enc Whh^T
#define B_DIHT 8388608u    // [512][2048] dec Wih^T
#define B_DHHT 12582912u   // [512][2048] dec Whh^T
#define B_XD   16777216u   // [2048][2048] enc x-dots, r=b*64+t
#define B_H    33554432u   // [2][32][512] ping-pong h
#define B_C    33685504u   // [2][32][512]
#define B_GT   33882112u   // [32][2048] gates
#define B_LG   34144256u   // [32][32000] logits, then shifted
#define B_PM   38240256u   // [32][512] partial max
#define B_PS   38305792u   // [32][512] partial sums
#define B_PK   38371328u   // u64 [32][512] argmax partials

// ---- d_out layout (f32 element offsets) ----
#define OUT_TOK  0u
#define OUT_LOGP 2048u
#define OUT_ENC  65538048u

__device__ __forceinline__ unsigned long long packkey(float x, int v) {
    unsigned int fb = __float_as_uint(x);
    unsigned int key = (fb & 0x80000000u) ? ~fb : (fb | 0x80000000u);
    return ((unsigned long long)key << 32) | (unsigned int)(~(unsigned int)v);
}
__device__ __forceinline__ float sigf(float x) { return 1.0f / (1.0f + expf(-x)); }

// ---- transpose f32 [2048][512] -> [512][2048]
__global__ void k_tr(const float* __restrict__ src, float* __restrict__ dst) {
    __shared__ float lds[32][33];
    int c0 = blockIdx.x * 32, r0 = blockIdx.y * 32;
    int cl = threadIdx.x & 31, r8 = threadIdx.x >> 5;
    for (int rr = 0; rr < 4; ++rr) {
        int r = r8 + rr * 8;
        lds[r][cl] = src[(size_t)(r0 + r) * HID + c0 + cl];
    }
    __syncthreads();
    for (int rr = 0; rr < 4; ++rr) {
        int idx = threadIdx.x + rr * 256;
        int rl = idx & 31, c2 = idx >> 5;
        dst[(size_t)(c0 + c2) * 2048 + r0 + rl] = lds[rl][c2];
    }
}

// ---- zero parity-0 h,c
__global__ void k_zero(char* __restrict__ ws) {
    int i = blockIdx.x * 256 + threadIdx.x;   // 16384
    ((float*)(ws + B_H))[i] = 0.f;
    ((float*)(ws + B_C))[i] = 0.f;
}

// ---- enc x-dots: XD[r][j4] = fmaf-chain_k( WihT[k][j4] * emb[x[r]][k] )
__global__ void __launch_bounds__(256) k_xd(const int* __restrict__ x, const float* __restrict__ emb,
                                            char* __restrict__ ws) {
    __shared__ float e_s[512];
    int r = blockIdx.x;                        // 0..2047 (= b*64+t)
    int j4 = blockIdx.y * 256 + threadIdx.x;   // 0..2047
    const float* erow = emb + (size_t)x[r] * HID;
    for (int k = threadIdx.x; k < HID; k += 256) e_s[k] = erow[k];
    __syncthreads();
    const float* WT = (const float*)(ws + B_EIHT);
    float acc = 0.f;
    for (int k = 0; k < HID; ++k)
        acc = fmaf(WT[(size_t)k * 2048 + j4], e_s[k], acc);
    ((float*)(ws + B_XD))[(size_t)r * 2048 + j4] = acc;
}

// ---- gates (fused token-reduce + e-gather for decoder)
// grid 256: b = bid>>3, jc = bid&7, j4 = jc*256+tid
__global__ void __launch_bounds__(256) k_gates(const float* __restrict__ bih,
                                               const float* __restrict__ bhh,
                                               const float* __restrict__ emb,
                                               const int* __restrict__ sos,
                                               const float* __restrict__ Hin,
                                               char* __restrict__ ws,
                                               float* __restrict__ dout,
                                               int t, int mode) {
    __shared__ float e_s[512];
    __shared__ unsigned long long psh[4];
    __shared__ int toksh;
    int b = blockIdx.x >> 3, jc = blockIdx.x & 7;
    int j4 = jc * 256 + threadIdx.x;
    const float* hb = Hin + b * HID;

    if (mode == 1) {
        int tok;
        if (t == 0) {
            tok = sos[0];
        } else {
            // order-free u64 max over PK[b][0..500) (replicates finT result exactly)
            const unsigned long long* pkr = (const unsigned long long*)(ws + B_PK) + b * 512;
            unsigned long long pk = 0ull;
            for (int c = threadIdx.x; c < 500; c += 256) {
                unsigned long long o = pkr[c];
                if (o > pk) pk = o;
            }
#pragma unroll
            for (int m = 1; m < 64; m <<= 1) {
                unsigned long long o = __shfl_xor(pk, m);
                if (o > pk) pk = o;
            }
            if ((threadIdx.x & 63) == 0) psh[threadIdx.x >> 6] = pk;
            __syncthreads();
            if (threadIdx.x == 0) {
                pk = psh[0];
                if (psh[1] > pk) pk = psh[1];
                if (psh[2] > pk) pk = psh[2];
                if (psh[3] > pk) pk = psh[3];
                int v = (int)(~(unsigned)(pk & 0xFFFFFFFFull));
                toksh = v;
                if (jc == 0) dout[OUT_TOK + b * SEQ + (t - 1)] = (float)v;
            }
            __syncthreads();
            tok = toksh;
        }
        const float* erow = emb + (size_t)tok * HID;
        e_s[threadIdx.x] = erow[threadIdx.x];
        e_s[threadIdx.x + 256] = erow[threadIdx.x + 256];
        __syncthreads();

        const float* WI = (const float*)(ws + B_DIHT);
        const float* WH = (const float*)(ws + B_DHHT);
        float aI = 0.f, aH = 0.f;
        for (int k = 0; k < HID; ++k) {          // two independent chains, each ascending k
            aI = fmaf(WI[(size_t)k * 2048 + j4], e_s[k], aI);
            aH = fmaf(WH[(size_t)k * 2048 + j4], hb[k], aH);
        }
        float g = (aI + aH) + bih[j4];
        g = g + bhh[j4];
        ((float*)(ws + B_GT))[b * 2048 + j4] = g;
    } else {
        const float* WH = (const float*)(ws + B_EHHT);
        float aH = 0.f;
        for (int k = 0; k < HID; ++k)
            aH = fmaf(WH[(size_t)k * 2048 + j4], hb[k], aH);
        float xd = ((const float*)(ws + B_XD))[(size_t)(b * SEQ + t) * 2048 + j4];
        float g = (xd + aH) + bih[j4];
        g = g + bhh[j4];
        ((float*)(ws + B_GT))[b * 2048 + j4] = g;
    }
}

// ---- cell: f32 per-op (verbatim from passing kernel)
__global__ void k_cell(char* __restrict__ ws,
                       const float* __restrict__ Cin,
                       float* __restrict__ Hout, float* __restrict__ Cout,
                       float* __restrict__ dout, int t, int mode) {
    int i = blockIdx.x * 256 + threadIdx.x;   // 16384
    int b = i >> 9, j = i & 511;
    const float* gb = (const float*)(ws + B_GT) + b * 2048;
    float ip = sigf(gb[j]);
    float fp = sigf(gb[512 + j]);
    float gp = tanhf(gb[1024 + j]);
    float op = sigf(gb[1536 + j]);
    float cn = fp * Cin[i] + ip * gp;
    float hn = op * tanhf(cn);
    Hout[i] = hn;
    Cout[i] = cn;
    if (mode == 0)
        dout[OUT_ENC + (size_t)b * (SEQ * HID) + (size_t)t * HID + j] = hn;
}

// ---- logits: grid (125,4), acc[8], h via wave-uniform global loads (no LDS)
__global__ void __launch_bounds__(256) k_logits(const float* __restrict__ Hin,
                                                const float* __restrict__ Wout,
                                                const float* __restrict__ bout,
                                                char* __restrict__ ws) {
    int vb = blockIdx.x, bh = blockIdx.y;     // vb 0..124, bh 0..3
    int v = vb * 256 + threadIdx.x;
    const float* wr = Wout + (size_t)v * HID;
    float acc[8];
#pragma unroll
    for (int i = 0; i < 8; ++i) acc[i] = 0.f;
    for (int k = 0; k < HID; k += 4) {
        float4 w = *(const float4*)&wr[k];
#pragma unroll
        for (int bb = 0; bb < 8; ++bb) {
            float4 h4 = *(const float4*)&Hin[(size_t)(bh * 8 + bb) * HID + k];  // uniform -> SMEM
            float a = acc[bb];
            a = fmaf(w.x, h4.x, a);           // strictly ascending k, single accumulator
            a = fmaf(w.y, h4.y, a);
            a = fmaf(w.z, h4.z, a);
            a = fmaf(w.w, h4.w, a);
            acc[bb] = a;
        }
    }
    float bq = bout[v];
    float mx[8];
#pragma unroll
    for (int bb = 0; bb < 8; ++bb) {
        float lg = acc[bb] + bq;
        ((float*)(ws + B_LG))[(size_t)(bh * 8 + bb) * VOC + v] = lg;
        mx[bb] = lg;
    }
#pragma unroll
    for (int m = 1; m < 64; m <<= 1)
#pragma unroll
        for (int bb = 0; bb < 8; ++bb) mx[bb] = fmaxf(mx[bb], __shfl_xor(mx[bb], m));
    if ((threadIdx.x & 63) == 0) {
        int col = vb * 4 + (threadIdx.x >> 6);
#pragma unroll
        for (int bb = 0; bb < 8; ++bb)
            ((float*)(ws + B_PM))[(bh * 8 + bb) * 512 + col] = mx[bb];
    }
}

// ---- passB: inline row-max (order-free) + shifted + exp + partial sums (orders verbatim)
__global__ void __launch_bounds__(256) k_passB(char* __restrict__ ws) {
    __shared__ float msh[2][4];
    int vb = blockIdx.x, bg = blockIdx.y;
    int b0 = bg * 2;
    int v = vb * 256 + threadIdx.x;
    // inline finM replica: fmax over PM[b][0..500) — order-independent
    float m0 = -3.4e38f, m1 = -3.4e38f;
    const float* pm0 = (const float*)(ws + B_PM) + b0 * 512;
    const float* pm1 = (const float*)(ws + B_PM) + (b0 + 1) * 512;
    for (int c = threadIdx.x; c < 500; c += 256) {
        m0 = fmaxf(m0, pm0[c]);
        m1 = fmaxf(m1, pm1[c]);
    }
#pragma unroll
    for (int k = 1; k < 64; k <<= 1) {
        m0 = fmaxf(m0, __shfl_xor(m0, k));
        m1 = fmaxf(m1, __shfl_xor(m1, k));
    }
    if ((threadIdx.x & 63) == 0) {
        msh[0][threadIdx.x >> 6] = m0;
        msh[1][threadIdx.x >> 6] = m1;
    }
    __syncthreads();
    float M[2];
    M[0] = fmaxf(fmaxf(msh[0][0], msh[0][1]), fmaxf(msh[0][2], msh[0][3]));
    M[1] = fmaxf(fmaxf(msh[1][0], msh[1][1]), fmaxf(msh[1][2], msh[1][3]));

    float e2[2];
#pragma unroll
    for (int row = 0; row < 2; ++row) {
        int b = b0 + row;
        float* p = (float*)(ws + B_LG) + (size_t)b * VOC + v;
        float sv = *p - M[row];
        *p = sv;
        e2[row] = expf(sv);
    }
#pragma unroll
    for (int m = 1; m < 64; m <<= 1) {
        e2[0] += __shfl_xor(e2[0], m);
        e2[1] += __shfl_xor(e2[1], m);
    }
    if ((threadIdx.x & 63) == 0) {
        int col = vb * 4 + (threadIdx.x >> 6);
        ((float*)(ws + B_PS))[b0 * 512 + col] = e2[0];
        ((float*)(ws + B_PS))[(b0 + 1) * 512 + col] = e2[1];
    }
}

// ---- passC: inline lse (exact finS replica) + logp write + argmax partials (verbatim)
__global__ void __launch_bounds__(256) k_passC(char* __restrict__ ws, float* __restrict__ dout, int t) {
    __shared__ float ssh0[4], ssh1[4];
    int vb = blockIdx.x, bg = blockIdx.y;
    int b0 = bg * 2;
    int v = vb * 256 + threadIdx.x;
    // exact finS replica for both rows: same lane mapping, butterfly, 4-slot chain, logf
    const float* ps0 = (const float*)(ws + B_PS) + b0 * 512;
    const float* ps1 = (const float*)(ws + B_PS) + (b0 + 1) * 512;
    float s0 = 0.f, s1 = 0.f;
    for (int c = threadIdx.x; c < 500; c += 256) {
        s0 += ps0[c];
        s1 += ps1[c];
    }
#pragma unroll
    for (int k = 1; k < 64; k <<= 1) {
        s0 += __shfl_xor(s0, k);
        s1 += __shfl_xor(s1, k);
    }
    if ((threadIdx.x & 63) == 0) {
        ssh0[threadIdx.x >> 6] = s0;
        ssh1[threadIdx.x >> 6] = s1;
    }
    __syncthreads();
    float L[2];
    L[0] = logf(((ssh0[0] + ssh0[1]) + ssh0[2]) + ssh0[3]);
    L[1] = logf(((ssh1[0] + ssh1[1]) + ssh1[2]) + ssh1[3]);

    unsigned long long pk2[2];
#pragma unroll
    for (int row = 0; row < 2; ++row) {
        int b = b0 + row;
        float sv = ((const float*)(ws + B_LG))[(size_t)b * VOC + v];
        float lp = sv - L[row];
        dout[OUT_LOGP + (size_t)(b * SEQ + t) * VOC + v] = lp;
        pk2[row] = packkey(lp, v);
    }
#pragma unroll
    for (int m = 1; m < 64; m <<= 1) {
#pragma unroll
        for (int row = 0; row < 2; ++row) {
            unsigned long long o = __shfl_xor(pk2[row], m);
            if (o > pk2[row]) pk2[row] = o;
        }
    }
    if ((threadIdx.x & 63) == 0) {
        int col = vb * 4 + (threadIdx.x >> 6);
        ((unsigned long long*)(ws + B_PK))[b0 * 512 + col] = pk2[0];
        ((unsigned long long*)(ws + B_PK))[(b0 + 1) * 512 + col] = pk2[1];
    }
}

// ---- final token write for t=63
__global__ void k_tokfin(char* __restrict__ ws, float* __restrict__ dout) {
    __shared__ unsigned long long sh[4];
    int b = blockIdx.x;
    unsigned long long pk = 0ull;
    for (int c = threadIdx.x; c < 500; c += 256) {
        unsigned long long o = ((const unsigned long long*)(ws + B_PK))[b * 512 + c];
        if (o > pk) pk = o;
    }
#pragma unroll
    for (int k = 1; k < 64; k <<= 1) {
        unsigned long long o = __shfl_xor(pk, k);
        if (o > pk) pk = o;
    }
    if ((threadIdx.x & 63) == 0) sh[threadIdx.x >> 6] = pk;
    __syncthreads();
    if (threadIdx.x == 0) {
        pk = sh[0];
        if (sh[1] > pk) pk = sh[1];
        if (sh[2] > pk) pk = sh[2];
        if (sh[3] > pk) pk = sh[3];
        int v = (int)(~(unsigned)(pk & 0xFFFFFFFFull));
        dout[OUT_TOK + b * SEQ + 63] = (float)v;
    }
}

extern "C" void kernel_launch(void* const* d_in, const int* in_sizes, int n_in,
                              void* d_out, int out_size, void* d_ws, size_t ws_size,
                              hipStream_t stream) {
    const int*   x    = (const int*)d_in[0];
    const float* emb  = (const float*)d_in[1];
    const float* eWih = (const float*)d_in[2];
    const float* eWhh = (const float*)d_in[3];
    const float* ebih = (const float*)d_in[4];
    const float* ebhh = (const float*)d_in[5];
    const float* dWih = (const float*)d_in[6];
    const float* dWhh = (const float*)d_in[7];
    const float* dbih = (const float*)d_in[8];
    const float* dbhh = (const float*)d_in[9];
    const float* Wout = (const float*)d_in[10];
    const float* bout = (const float*)d_in[11];
    const int*   sos  = (const int*)d_in[12];
    float* out = (float*)d_out;
    char*  ws  = (char*)d_ws;

    float* H = (float*)(ws + B_H);   // parity stride 16384 floats
    float* C = (float*)(ws + B_C);

    hipLaunchKernelGGL(k_tr, dim3(16, 64), dim3(256), 0, stream, eWih, (float*)(ws + B_EIHT));
    hipLaunchKernelGGL(k_tr, dim3(16, 64), dim3(256), 0, stream, eWhh, (float*)(ws + B_EHHT));
    hipLaunchKernelGGL(k_tr, dim3(16, 64), dim3(256), 0, stream, dWih, (float*)(ws + B_DIHT));
    hipLaunchKernelGGL(k_tr, dim3(16, 64), dim3(256), 0, stream, dWhh, (float*)(ws + B_DHHT));
    hipLaunchKernelGGL(k_xd, dim3(2048, 8), dim3(256), 0, stream, x, emb, ws);
    hipLaunchKernelGGL(k_zero, dim3(64), dim3(256), 0, stream, ws);

    for (int t = 0; t < SEQ; ++t) {
        int pi = t & 1, po = pi ^ 1;
        hipLaunchKernelGGL(k_gates, dim3(256), dim3(256), 0, stream,
                           ebih, ebhh, emb, sos, H + pi * 16384, ws, out, t, 0);
        hipLaunchKernelGGL(k_cell, dim3(64), dim3(256), 0, stream,
                           ws, C + pi * 16384, H + po * 16384, C + po * 16384, out, t, 0);
    }
    for (int t = 0; t < SEQ; ++t) {
        int pi = t & 1, po = pi ^ 1;
        hipLaunchKernelGGL(k_gates, dim3(256), dim3(256), 0, stream,
                           dbih, dbhh, emb, sos, H + pi * 16384, ws, out, t, 1);
        hipLaunchKernelGGL(k_cell, dim3(64), dim3(256), 0, stream,
                           ws, C + pi * 16384, H + po * 16384, C + po * 16384, out, t, 1);
        hipLaunchKernelGGL(k_logits, dim3(125, 4), dim3(256), 0, stream,
                           H + po * 16384, Wout, bout, ws);
        hipLaunchKernelGGL(k_passB, dim3(125, 16), dim3(256), 0, stream, ws);
        hipLaunchKernelGGL(k_passC, dim3(125, 16), dim3(256), 0, stream, ws, out, t);
    }
    hipLaunchKernelGGL(k_tokfin, dim3(32), dim3(256), 0, stream, ws, out);
}